// Round 1
// baseline (793.143 us; speedup 1.0000x reference)
//
#include <hip/hip_runtime.h>

// Problem constants (match reference)
#define U_NODES 100000
#define I_NODES 50000
#define N_NODES 150000   // U + I
#define EMB_D   64
#define FEAT_K  256
#define N_LAYERS 4

// ---------------------------------------------------------------------------
// CSR build: degree count
__global__ __launch_bounds__(256) void k_count(const int* __restrict__ col,
                                               int* __restrict__ deg, int E) {
    int e = blockIdx.x * 256 + threadIdx.x;
    if (e < E) atomicAdd(&deg[col[e]], 1);
}

// dinv[i] = deg>0 ? rsqrt(deg) : 0
__global__ __launch_bounds__(256) void k_dinv(const int* __restrict__ deg,
                                              float* __restrict__ dinv, int n) {
    int i = blockIdx.x * 256 + threadIdx.x;
    if (i < n) {
        int d = deg[i];
        dinv[i] = (d > 0) ? rsqrtf((float)d) : 0.0f;
    }
}

// Scan stage A: per-block (256-elem) exclusive scan of deg -> rs, block totals -> bsum
__global__ __launch_bounds__(256) void k_scan_a(const int* __restrict__ deg,
                                                int* __restrict__ rs,
                                                int* __restrict__ bsum, int n) {
    __shared__ int wsum[4];
    int t = threadIdx.x;
    int i = blockIdx.x * 256 + t;
    int v = (i < n) ? deg[i] : 0;
    int x = v;
    #pragma unroll
    for (int off = 1; off < 64; off <<= 1) {
        int y = __shfl_up(x, off, 64);
        if ((t & 63) >= off) x += y;
    }
    if ((t & 63) == 63) wsum[t >> 6] = x;
    __syncthreads();
    int base = 0;
    #pragma unroll
    for (int w = 0; w < 4; ++w) base += (w < (t >> 6)) ? wsum[w] : 0;
    if (i < n) rs[i] = base + x - v;           // exclusive within block
    if (t == 255) bsum[blockIdx.x] = base + x; // block total
}

// Scan stage B: single block (1024 threads) exclusive scan of block sums in place
__global__ __launch_bounds__(1024) void k_scan_b(int* __restrict__ bs, int nb) {
    __shared__ int wsum[16];
    int t = threadIdx.x;
    int v = (t < nb) ? bs[t] : 0;
    int x = v;
    #pragma unroll
    for (int off = 1; off < 64; off <<= 1) {
        int y = __shfl_up(x, off, 64);
        if ((t & 63) >= off) x += y;
    }
    if ((t & 63) == 63) wsum[t >> 6] = x;
    __syncthreads();
    int base = 0;
    #pragma unroll
    for (int w = 0; w < 16; ++w) base += (w < (t >> 6)) ? wsum[w] : 0;
    if (t < nb) bs[t] = base + x - v;
}

// Scan stage C: add block offsets, copy to cursor, set rs[n]=E
__global__ __launch_bounds__(256) void k_scan_c(int* __restrict__ rs,
                                                const int* __restrict__ bsum,
                                                int* __restrict__ cursor,
                                                int n, int E) {
    int i = blockIdx.x * 256 + threadIdx.x;
    if (i < n) {
        int v = rs[i] + bsum[blockIdx.x];
        rs[i] = v;
        cursor[i] = v;
    }
    if (i == 0) rs[n] = E;
}

// CSR fill: place each edge into its destination's segment; precompute norm
__global__ __launch_bounds__(256) void k_fill(const int* __restrict__ row,
                                              const int* __restrict__ col,
                                              const float* __restrict__ dinv,
                                              int* __restrict__ cursor,
                                              int* __restrict__ csr_src,
                                              float* __restrict__ csr_nrm, int E) {
    int e = blockIdx.x * 256 + threadIdx.x;
    if (e < E) {
        int r = row[e], c = col[e];
        int p = atomicAdd(&cursor[c], 1);
        csr_src[p] = r;
        csr_nrm[p] = dinv[r] * dinv[c];
    }
}

// Init: x0 = concat(emb_users, emb_items); acc (= d_out) = x0
__global__ __launch_bounds__(256) void k_init(const float4* __restrict__ eu,
                                              const float4* __restrict__ ei,
                                              float4* __restrict__ x,
                                              float4* __restrict__ acc,
                                              int n16u, int n16) {
    int i = blockIdx.x * 256 + threadIdx.x;
    if (i < n16) {
        float4 v = (i < n16u) ? eu[i] : ei[i - n16u];
        x[i] = v;
        acc[i] = v;
    }
}

// Pull-mode aggregation: 16 lanes per node, each owns one float4 of the row.
// x_next[c] = sum_{e in CSR[c]} x_cur[src[e]] * nrm[e];  acc[c] += x_next[c]
__global__ __launch_bounds__(256) void k_agg(const float4* __restrict__ xin,
                                             float4* __restrict__ xout,
                                             float4* __restrict__ acc,
                                             const int* __restrict__ rs,
                                             const int* __restrict__ src,
                                             const float* __restrict__ nrm,
                                             int n_nodes) {
    int idx = blockIdx.x * 256 + threadIdx.x;
    int node = idx >> 4;
    int lane = idx & 15;
    if (node >= n_nodes) return;
    int e0 = rs[node], e1 = rs[node + 1];
    float4 s = make_float4(0.f, 0.f, 0.f, 0.f);
    for (int e = e0; e < e1; ++e) {
        int sn = src[e];            // broadcast across the 16 lanes
        float w = nrm[e];
        float4 v = xin[(size_t)sn * 16 + lane];   // 256B coalesced per edge
        s.x = fmaf(v.x, w, s.x);
        s.y = fmaf(v.y, w, s.y);
        s.z = fmaf(v.z, w, s.z);
        s.w = fmaf(v.w, w, s.w);
    }
    size_t o = (size_t)node * 16 + lane;
    xout[o] = s;
    float4 a = acc[o];
    a.x += s.x; a.y += s.y; a.z += s.z; a.w += s.w;
    acc[o] = a;
}

// Projection epilogue: out[r][:] = out[r][:] * (1/25) + F[r] @ W^T
// One thread per row; W reads are wave-uniform -> scalar loads.
__global__ __launch_bounds__(256) void k_proj(const float* __restrict__ F,
                                              const float* __restrict__ W,
                                              float* __restrict__ out, int M) {
    int r = blockIdx.x * 256 + threadIdx.x;
    if (r >= M) return;
    const float4* f4 = (const float4*)(F + (size_t)r * FEAT_K);
    const float4* w4 = (const float4*)W;   // [64][64] float4 view of [64][256]
    float acc[EMB_D];
    #pragma unroll
    for (int j = 0; j < EMB_D; ++j) acc[j] = 0.f;
    for (int k4 = 0; k4 < FEAT_K / 4; ++k4) {
        float4 f = f4[k4];
        #pragma unroll
        for (int j = 0; j < EMB_D; ++j) {
            float4 w = w4[j * (FEAT_K / 4) + k4];  // uniform -> s_load_dwordx4
            acc[j] = fmaf(f.x, w.x, acc[j]);
            acc[j] = fmaf(f.y, w.y, acc[j]);
            acc[j] = fmaf(f.z, w.z, acc[j]);
            acc[j] = fmaf(f.w, w.w, acc[j]);
        }
    }
    const float scale = 1.0f / 25.0f;
    float4* o4 = (float4*)(out + (size_t)r * EMB_D);
    #pragma unroll
    for (int j4 = 0; j4 < EMB_D / 4; ++j4) {
        float4 t = o4[j4];
        t.x = t.x * scale + acc[j4 * 4 + 0];
        t.y = t.y * scale + acc[j4 * 4 + 1];
        t.z = t.z * scale + acc[j4 * 4 + 2];
        t.w = t.w * scale + acc[j4 * 4 + 3];
        o4[j4] = t;
    }
}

// ---------------------------------------------------------------------------
extern "C" void kernel_launch(void* const* d_in, const int* in_sizes, int n_in,
                              void* d_out, int out_size, void* d_ws, size_t ws_size,
                              hipStream_t stream) {
    const int E = in_sizes[0] / 2;
    const int N = N_NODES, U = U_NODES;

    const int*   edge  = (const int*)d_in[0];
    const float* emb_u = (const float*)d_in[1];
    const float* emb_i = (const float*)d_in[2];
    const float* fu    = (const float*)d_in[3];
    const float* fi    = (const float*)d_in[4];
    const float* wu    = (const float*)d_in[5];
    const float* wi    = (const float*)d_in[6];
    const int* row = edge;
    const int* col = edge + E;

    // Workspace carve (aligned 256B). Total ~87 MB.
    char* p = (char*)d_ws;
    auto carve = [&](size_t bytes) -> void* {
        void* q = (void*)p;
        p += (bytes + 255) & ~(size_t)255;
        return q;
    };
    float* dinv    = (float*)carve((size_t)N * 4);
    int*   deg     = (int*)  carve((size_t)N * 4);
    int*   rs      = (int*)  carve((size_t)(N + 1) * 4);
    int*   cursor  = (int*)  carve((size_t)N * 4);
    int*   bsum    = (int*)  carve(1024 * 4);
    int*   csr_src = (int*)  carve((size_t)E * 4);
    float* csr_nrm = (float*)carve((size_t)E * 4);
    float* x_a     = (float*)carve((size_t)N * EMB_D * 4);
    float* x_b     = (float*)carve((size_t)N * EMB_D * 4);

    float* acc = (float*)d_out;   // acc lives in d_out: [N][64] == [u_final; i_final]

    const int NB = (N + 255) / 256;              // 586 scan blocks
    const int EB = (E + 255) / 256;              // edge blocks
    const int XB = ((N * 16) + 255) / 256;       // N*16 float4 elements

    // 1) degree
    hipMemsetAsync(deg, 0, (size_t)N * 4, stream);
    k_count<<<EB, 256, 0, stream>>>(col, deg, E);
    // 2) dinv
    k_dinv<<<NB, 256, 0, stream>>>(deg, dinv, N);
    // 3) exclusive scan deg -> rs (row starts), cursor copy
    k_scan_a<<<NB, 256, 0, stream>>>(deg, rs, bsum, N);
    k_scan_b<<<1, 1024, 0, stream>>>(bsum, NB);
    k_scan_c<<<NB, 256, 0, stream>>>(rs, bsum, cursor, N, E);
    // 4) CSR fill with precomputed norms
    k_fill<<<EB, 256, 0, stream>>>(row, col, dinv, cursor, csr_src, csr_nrm, E);
    // 5) x0 and acc init
    k_init<<<XB, 256, 0, stream>>>((const float4*)emb_u, (const float4*)emb_i,
                                   (float4*)x_a, (float4*)acc, U * 16, N * 16);
    // 6) 4 propagation layers (pull-mode, no atomics)
    float* xc = x_a; float* xn = x_b;
    for (int l = 0; l < N_LAYERS; ++l) {
        k_agg<<<XB, 256, 0, stream>>>((const float4*)xc, (float4*)xn, (float4*)acc,
                                      rs, csr_src, csr_nrm, N);
        float* t = xc; xc = xn; xn = t;
    }
    // 7) projection epilogue: out = out/25 + F @ W^T
    k_proj<<<(U + 255) / 256, 256, 0, stream>>>(fu, wu, acc, U);
    k_proj<<<(N - U + 255) / 256, 256, 0, stream>>>(fi, wi, acc + (size_t)U * EMB_D, N - U);
}

// Round 2
// 514.196 us; speedup vs baseline: 1.5425x; 1.5425x over previous
//
#include <hip/hip_runtime.h>

// Problem constants (match reference)
#define U_NODES 100000
#define I_NODES 50000
#define N_NODES 150000   // U + I
#define EMB_D   64
#define FEAT_K  256
#define N_LAYERS 4

// ---------------------------------------------------------------------------
// CSR build: degree count
__global__ __launch_bounds__(256) void k_count(const int* __restrict__ col,
                                               int* __restrict__ deg, int E) {
    int e = blockIdx.x * 256 + threadIdx.x;
    if (e < E) atomicAdd(&deg[col[e]], 1);
}

// dinv[i] = deg>0 ? rsqrt(deg) : 0
__global__ __launch_bounds__(256) void k_dinv(const int* __restrict__ deg,
                                              float* __restrict__ dinv, int n) {
    int i = blockIdx.x * 256 + threadIdx.x;
    if (i < n) {
        int d = deg[i];
        dinv[i] = (d > 0) ? rsqrtf((float)d) : 0.0f;
    }
}

// Scan stage A: per-block (256-elem) exclusive scan of deg -> rs, block totals -> bsum
__global__ __launch_bounds__(256) void k_scan_a(const int* __restrict__ deg,
                                                int* __restrict__ rs,
                                                int* __restrict__ bsum, int n) {
    __shared__ int wsum[4];
    int t = threadIdx.x;
    int i = blockIdx.x * 256 + t;
    int v = (i < n) ? deg[i] : 0;
    int x = v;
    #pragma unroll
    for (int off = 1; off < 64; off <<= 1) {
        int y = __shfl_up(x, off, 64);
        if ((t & 63) >= off) x += y;
    }
    if ((t & 63) == 63) wsum[t >> 6] = x;
    __syncthreads();
    int base = 0;
    #pragma unroll
    for (int w = 0; w < 4; ++w) base += (w < (t >> 6)) ? wsum[w] : 0;
    if (i < n) rs[i] = base + x - v;           // exclusive within block
    if (t == 255) bsum[blockIdx.x] = base + x; // block total
}

// Scan stage B: single block (1024 threads) exclusive scan of block sums in place
__global__ __launch_bounds__(1024) void k_scan_b(int* __restrict__ bs, int nb) {
    __shared__ int wsum[16];
    int t = threadIdx.x;
    int v = (t < nb) ? bs[t] : 0;
    int x = v;
    #pragma unroll
    for (int off = 1; off < 64; off <<= 1) {
        int y = __shfl_up(x, off, 64);
        if ((t & 63) >= off) x += y;
    }
    if ((t & 63) == 63) wsum[t >> 6] = x;
    __syncthreads();
    int base = 0;
    #pragma unroll
    for (int w = 0; w < 16; ++w) base += (w < (t >> 6)) ? wsum[w] : 0;
    if (t < nb) bs[t] = base + x - v;
}

// Scan stage C: add block offsets, copy to cursor, set rs[n]=E
__global__ __launch_bounds__(256) void k_scan_c(int* __restrict__ rs,
                                                const int* __restrict__ bsum,
                                                int* __restrict__ cursor,
                                                int n, int E) {
    int i = blockIdx.x * 256 + threadIdx.x;
    if (i < n) {
        int v = rs[i] + bsum[blockIdx.x];
        rs[i] = v;
        cursor[i] = v;
    }
    if (i == 0) rs[n] = E;
}

// CSR fill: place each edge into its destination's segment; precompute norm
__global__ __launch_bounds__(256) void k_fill(const int* __restrict__ row,
                                              const int* __restrict__ col,
                                              const float* __restrict__ dinv,
                                              int* __restrict__ cursor,
                                              int* __restrict__ csr_src,
                                              float* __restrict__ csr_nrm, int E) {
    int e = blockIdx.x * 256 + threadIdx.x;
    if (e < E) {
        int r = row[e], c = col[e];
        int p = atomicAdd(&cursor[c], 1);
        csr_src[p] = r;
        csr_nrm[p] = dinv[r] * dinv[c];
    }
}

// Init: x0 = concat(emb_users, emb_items); acc (= d_out) = x0
__global__ __launch_bounds__(256) void k_init(const float4* __restrict__ eu,
                                              const float4* __restrict__ ei,
                                              float4* __restrict__ x,
                                              float4* __restrict__ acc,
                                              int n16u, int n16) {
    int i = blockIdx.x * 256 + threadIdx.x;
    if (i < n16) {
        float4 v = (i < n16u) ? eu[i] : ei[i - n16u];
        x[i] = v;
        acc[i] = v;
    }
}

// Pull-mode aggregation: 16 lanes per node, each owns one float4 of the row.
// x_next[c] = sum_{e in CSR[c]} x_cur[src[e]] * nrm[e];  acc[c] += x_next[c]
__global__ __launch_bounds__(256) void k_agg(const float4* __restrict__ xin,
                                             float4* __restrict__ xout,
                                             float4* __restrict__ acc,
                                             const int* __restrict__ rs,
                                             const int* __restrict__ src,
                                             const float* __restrict__ nrm,
                                             int n_nodes) {
    int idx = blockIdx.x * 256 + threadIdx.x;
    int node = idx >> 4;
    int lane = idx & 15;
    if (node >= n_nodes) return;
    int e0 = rs[node], e1 = rs[node + 1];
    float4 s = make_float4(0.f, 0.f, 0.f, 0.f);
    for (int e = e0; e < e1; ++e) {
        int sn = src[e];            // broadcast across the 16 lanes
        float w = nrm[e];
        float4 v = xin[(size_t)sn * 16 + lane];   // 256B coalesced per edge
        s.x = fmaf(v.x, w, s.x);
        s.y = fmaf(v.y, w, s.y);
        s.z = fmaf(v.z, w, s.z);
        s.w = fmaf(v.w, w, s.w);
    }
    size_t o = (size_t)node * 16 + lane;
    xout[o] = s;
    float4 a = acc[o];
    a.x += s.x; a.y += s.y; a.z += s.z; a.w += s.w;
    acc[o] = a;
}

// ---------------------------------------------------------------------------
// Projection: C[M,64] = F[M,256] @ W[64,256]^T, fused epilogue
//   out[r][c] = out[r][c]/25 + C[r][c]
// Tiled f32 GEMM: block = 256 threads -> 256x64 output tile, BK=32,
// per-thread 8x8 register tile (static indices only -> stays in VGPRs).
#define BM   256
#define BK   32
#define SFT_STRIDE 260   // BM + 4 pad: row stride 1040B (16B-aligned, odd*16)
#define SW_STRIDE  68    // 64 + 4 pad: row stride 272B (16B-aligned)

__global__ __launch_bounds__(256) void k_proj(const float* __restrict__ F,
                                              const float* __restrict__ W,
                                              float* __restrict__ out, int M) {
    __shared__ float sFt[BK][SFT_STRIDE];   // F tile, transposed: [k][row], 33.3 KB
    __shared__ float sW[BK][SW_STRIDE];     // W tile, transposed: [k][n],   8.7 KB
    const int t  = threadIdx.x;
    const int rg = t >> 3;   // 0..31: row group (8 rows)
    const int cg = t & 7;    // 0..7 : col group (8 cols)
    const int row0 = blockIdx.x * BM;

    float acc[8][8];
    #pragma unroll
    for (int i = 0; i < 8; ++i)
        #pragma unroll
        for (int j = 0; j < 8; ++j) acc[i][j] = 0.f;

    for (int k0 = 0; k0 < FEAT_K; k0 += BK) {
        // Stage F tile transposed: 256 rows x 32 k. 2048 float4, 8 per thread.
        #pragma unroll
        for (int i = 0; i < 8; ++i) {
            int l = t + i * 256;          // 0..2047
            int r = l >> 3;               // 0..255
            int c4 = l & 7;               // which float4 of the 32-float k-slice
            int grow = row0 + r;
            float4 v = make_float4(0.f, 0.f, 0.f, 0.f);
            if (grow < M) v = ((const float4*)(F + (size_t)grow * FEAT_K + k0))[c4];
            sFt[c4 * 4 + 0][r] = v.x;
            sFt[c4 * 4 + 1][r] = v.y;
            sFt[c4 * 4 + 2][r] = v.z;
            sFt[c4 * 4 + 3][r] = v.w;
        }
        // Stage W tile transposed: 64 n-rows x 32 k. 512 float4, 2 per thread.
        #pragma unroll
        for (int i = 0; i < 2; ++i) {
            int l = t + i * 256;
            int n = l >> 3, c4 = l & 7;
            float4 v = ((const float4*)(W + (size_t)n * FEAT_K + k0))[c4];
            sW[c4 * 4 + 0][n] = v.x;
            sW[c4 * 4 + 1][n] = v.y;
            sW[c4 * 4 + 2][n] = v.z;
            sW[c4 * 4 + 3][n] = v.w;
        }
        __syncthreads();
        #pragma unroll
        for (int k = 0; k < BK; ++k) {
            float4 a0 = *(const float4*)&sFt[k][rg * 8];
            float4 a1 = *(const float4*)&sFt[k][rg * 8 + 4];
            float4 b0 = *(const float4*)&sW[k][cg * 8];
            float4 b1 = *(const float4*)&sW[k][cg * 8 + 4];
            float a[8] = {a0.x, a0.y, a0.z, a0.w, a1.x, a1.y, a1.z, a1.w};
            float b[8] = {b0.x, b0.y, b0.z, b0.w, b1.x, b1.y, b1.z, b1.w};
            #pragma unroll
            for (int ii = 0; ii < 8; ++ii)
                #pragma unroll
                for (int jj = 0; jj < 8; ++jj)
                    acc[ii][jj] = fmaf(a[ii], b[jj], acc[ii][jj]);
        }
        __syncthreads();
    }

    const float scale = 1.0f / 25.0f;
    #pragma unroll
    for (int ii = 0; ii < 8; ++ii) {
        int grow = row0 + rg * 8 + ii;
        if (grow < M) {
            float4* o4 = (float4*)(out + (size_t)grow * EMB_D + cg * 8);
            float4 t0 = o4[0], t1 = o4[1];
            t0.x = t0.x * scale + acc[ii][0];
            t0.y = t0.y * scale + acc[ii][1];
            t0.z = t0.z * scale + acc[ii][2];
            t0.w = t0.w * scale + acc[ii][3];
            t1.x = t1.x * scale + acc[ii][4];
            t1.y = t1.y * scale + acc[ii][5];
            t1.z = t1.z * scale + acc[ii][6];
            t1.w = t1.w * scale + acc[ii][7];
            o4[0] = t0;
            o4[1] = t1;
        }
    }
}

// ---------------------------------------------------------------------------
extern "C" void kernel_launch(void* const* d_in, const int* in_sizes, int n_in,
                              void* d_out, int out_size, void* d_ws, size_t ws_size,
                              hipStream_t stream) {
    const int E = in_sizes[0] / 2;
    const int N = N_NODES, U = U_NODES;

    const int*   edge  = (const int*)d_in[0];
    const float* emb_u = (const float*)d_in[1];
    const float* emb_i = (const float*)d_in[2];
    const float* fu    = (const float*)d_in[3];
    const float* fi    = (const float*)d_in[4];
    const float* wu    = (const float*)d_in[5];
    const float* wi    = (const float*)d_in[6];
    const int* row = edge;
    const int* col = edge + E;

    // Workspace carve (aligned 256B). Total ~87 MB.
    char* p = (char*)d_ws;
    auto carve = [&](size_t bytes) -> void* {
        void* q = (void*)p;
        p += (bytes + 255) & ~(size_t)255;
        return q;
    };
    float* dinv    = (float*)carve((size_t)N * 4);
    int*   deg     = (int*)  carve((size_t)N * 4);
    int*   rs      = (int*)  carve((size_t)(N + 1) * 4);
    int*   cursor  = (int*)  carve((size_t)N * 4);
    int*   bsum    = (int*)  carve(1024 * 4);
    int*   csr_src = (int*)  carve((size_t)E * 4);
    float* csr_nrm = (float*)carve((size_t)E * 4);
    float* x_a     = (float*)carve((size_t)N * EMB_D * 4);
    float* x_b     = (float*)carve((size_t)N * EMB_D * 4);

    float* acc = (float*)d_out;   // acc lives in d_out: [N][64] == [u_final; i_final]

    const int NB = (N + 255) / 256;              // 586 scan blocks
    const int EB = (E + 255) / 256;              // edge blocks
    const int XB = ((N * 16) + 255) / 256;       // N*16 float4 elements

    // 1) degree
    hipMemsetAsync(deg, 0, (size_t)N * 4, stream);
    k_count<<<EB, 256, 0, stream>>>(col, deg, E);
    // 2) dinv
    k_dinv<<<NB, 256, 0, stream>>>(deg, dinv, N);
    // 3) exclusive scan deg -> rs (row starts), cursor copy
    k_scan_a<<<NB, 256, 0, stream>>>(deg, rs, bsum, N);
    k_scan_b<<<1, 1024, 0, stream>>>(bsum, NB);
    k_scan_c<<<NB, 256, 0, stream>>>(rs, bsum, cursor, N, E);
    // 4) CSR fill with precomputed norms
    k_fill<<<EB, 256, 0, stream>>>(row, col, dinv, cursor, csr_src, csr_nrm, E);
    // 5) x0 and acc init
    k_init<<<XB, 256, 0, stream>>>((const float4*)emb_u, (const float4*)emb_i,
                                   (float4*)x_a, (float4*)acc, U * 16, N * 16);
    // 6) 4 propagation layers (pull-mode, no atomics)
    float* xc = x_a; float* xn = x_b;
    for (int l = 0; l < N_LAYERS; ++l) {
        k_agg<<<XB, 256, 0, stream>>>((const float4*)xc, (float4*)xn, (float4*)acc,
                                      rs, csr_src, csr_nrm, N);
        float* t = xc; xc = xn; xn = t;
    }
    // 7) projection epilogue: out = out/25 + F @ W^T
    k_proj<<<(U + BM - 1) / BM, 256, 0, stream>>>(fu, wu, acc, U);
    k_proj<<<(N - U + BM - 1) / BM, 256, 0, stream>>>(fi, wi, acc + (size_t)U * EMB_D, N - U);
}

// Round 3
// 452.433 us; speedup vs baseline: 1.7531x; 1.1365x over previous
//
#include <hip/hip_runtime.h>

// Problem constants (match reference)
#define U_NODES 100000
#define I_NODES 50000
#define N_NODES 150000   // U + I
#define EMB_D   64
#define FEAT_K  256
#define N_LAYERS 4

// ---------------------------------------------------------------------------
// CSR build: degree count
__global__ __launch_bounds__(256) void k_count(const int* __restrict__ col,
                                               int* __restrict__ deg, int E) {
    int e = blockIdx.x * 256 + threadIdx.x;
    if (e < E) atomicAdd(&deg[col[e]], 1);
}

// dinv[i] = deg>0 ? rsqrt(deg) : 0
__global__ __launch_bounds__(256) void k_dinv(const int* __restrict__ deg,
                                              float* __restrict__ dinv, int n) {
    int i = blockIdx.x * 256 + threadIdx.x;
    if (i < n) {
        int d = deg[i];
        dinv[i] = (d > 0) ? rsqrtf((float)d) : 0.0f;
    }
}

// Scan stage A: per-block (256-elem) exclusive scan of deg -> rs, block totals -> bsum
__global__ __launch_bounds__(256) void k_scan_a(const int* __restrict__ deg,
                                                int* __restrict__ rs,
                                                int* __restrict__ bsum, int n) {
    __shared__ int wsum[4];
    int t = threadIdx.x;
    int i = blockIdx.x * 256 + t;
    int v = (i < n) ? deg[i] : 0;
    int x = v;
    #pragma unroll
    for (int off = 1; off < 64; off <<= 1) {
        int y = __shfl_up(x, off, 64);
        if ((t & 63) >= off) x += y;
    }
    if ((t & 63) == 63) wsum[t >> 6] = x;
    __syncthreads();
    int base = 0;
    #pragma unroll
    for (int w = 0; w < 4; ++w) base += (w < (t >> 6)) ? wsum[w] : 0;
    if (i < n) rs[i] = base + x - v;           // exclusive within block
    if (t == 255) bsum[blockIdx.x] = base + x; // block total
}

// Scan stage B: single block (1024 threads) exclusive scan of block sums in place
__global__ __launch_bounds__(1024) void k_scan_b(int* __restrict__ bs, int nb) {
    __shared__ int wsum[16];
    int t = threadIdx.x;
    int v = (t < nb) ? bs[t] : 0;
    int x = v;
    #pragma unroll
    for (int off = 1; off < 64; off <<= 1) {
        int y = __shfl_up(x, off, 64);
        if ((t & 63) >= off) x += y;
    }
    if ((t & 63) == 63) wsum[t >> 6] = x;
    __syncthreads();
    int base = 0;
    #pragma unroll
    for (int w = 0; w < 16; ++w) base += (w < (t >> 6)) ? wsum[w] : 0;
    if (t < nb) bs[t] = base + x - v;
}

// Scan stage C: add block offsets, copy to cursor, set rs[n]=E
__global__ __launch_bounds__(256) void k_scan_c(int* __restrict__ rs,
                                                const int* __restrict__ bsum,
                                                int* __restrict__ cursor,
                                                int n, int E) {
    int i = blockIdx.x * 256 + threadIdx.x;
    if (i < n) {
        int v = rs[i] + bsum[blockIdx.x];
        rs[i] = v;
        cursor[i] = v;
    }
    if (i == 0) rs[n] = E;
}

// CSR fill: place each edge into its destination's segment; precompute norm
__global__ __launch_bounds__(256) void k_fill(const int* __restrict__ row,
                                              const int* __restrict__ col,
                                              const float* __restrict__ dinv,
                                              int* __restrict__ cursor,
                                              int* __restrict__ csr_src,
                                              float* __restrict__ csr_nrm, int E) {
    int e = blockIdx.x * 256 + threadIdx.x;
    if (e < E) {
        int r = row[e], c = col[e];
        int p = atomicAdd(&cursor[c], 1);
        csr_src[p] = r;
        csr_nrm[p] = dinv[r] * dinv[c];
    }
}

// Init: x0 = concat(emb_users, emb_items); acc (= d_out) = x0
__global__ __launch_bounds__(256) void k_init(const float4* __restrict__ eu,
                                              const float4* __restrict__ ei,
                                              float4* __restrict__ x,
                                              float4* __restrict__ acc,
                                              int n16u, int n16) {
    int i = blockIdx.x * 256 + threadIdx.x;
    if (i < n16) {
        float4 v = (i < n16u) ? eu[i] : ei[i - n16u];
        x[i] = v;
        acc[i] = v;
    }
}

// Pull-mode aggregation: 16 lanes per node, each owns one float4 of the row.
// x_next[c] = sum_{e in CSR[c]} x_cur[src[e]] * nrm[e];  acc[c] += x_next[c]
__global__ __launch_bounds__(256) void k_agg(const float4* __restrict__ xin,
                                             float4* __restrict__ xout,
                                             float4* __restrict__ acc,
                                             const int* __restrict__ rs,
                                             const int* __restrict__ src,
                                             const float* __restrict__ nrm,
                                             int n_nodes) {
    int idx = blockIdx.x * 256 + threadIdx.x;
    int node = idx >> 4;
    int lane = idx & 15;
    if (node >= n_nodes) return;
    int e0 = rs[node], e1 = rs[node + 1];
    float4 s = make_float4(0.f, 0.f, 0.f, 0.f);
    for (int e = e0; e < e1; ++e) {
        int sn = src[e];            // broadcast across the 16 lanes
        float w = nrm[e];
        float4 v = xin[(size_t)sn * 16 + lane];   // 256B coalesced per edge
        s.x = fmaf(v.x, w, s.x);
        s.y = fmaf(v.y, w, s.y);
        s.z = fmaf(v.z, w, s.z);
        s.w = fmaf(v.w, w, s.w);
    }
    size_t o = (size_t)node * 16 + lane;
    xout[o] = s;
    float4 a = acc[o];
    a.x += s.x; a.y += s.y; a.z += s.z; a.w += s.w;
    acc[o] = a;
}

// ---------------------------------------------------------------------------
// Projection: C[M,64] = F[M,256] @ W[64,256]^T, fused epilogue
//   out[r][c] = out[r][c]/25 + C[r][c]
// Both projections (user and item) run in ONE launch: blocks [0, nbU) do the
// user GEMM, blocks [nbU, nbU+nbI) the item GEMM.
// Tiled f32 GEMM: 256 threads -> 128x64 output tile, BK=32, per-thread 4x8
// register tile (static indices only -> stays in VGPRs).
// LDS 25.6 KB/block -> 6 blocks/CU cap; 1173 blocks ≈ 4.6/CU resident.
#define BM   128
#define BK   32
#define SFT_STRIDE 132   // BM + 4 pad: row stride 528B (16B-aligned)
#define SW_STRIDE  68    // 64 + 4 pad: row stride 272B (16B-aligned)

__global__ __launch_bounds__(256) void k_proj(const float* __restrict__ FU,
                                              const float* __restrict__ FI,
                                              const float* __restrict__ WU,
                                              const float* __restrict__ WI,
                                              float* __restrict__ out,
                                              int nbU, int U, int I) {
    __shared__ float sFt[BK][SFT_STRIDE];   // F tile, transposed: [k][row], 16.9 KB
    __shared__ float sW[BK][SW_STRIDE];     // W tile, transposed: [k][n],    8.7 KB

    const bool isU = ((int)blockIdx.x < nbU);
    const float* __restrict__ F = isU ? FU : FI;
    const float* __restrict__ W = isU ? WU : WI;
    float* __restrict__ o = isU ? out : out + (size_t)U * EMB_D;
    const int M = isU ? U : I;
    const int row0 = (isU ? (int)blockIdx.x : (int)blockIdx.x - nbU) * BM;

    const int t  = threadIdx.x;
    const int rg = t >> 3;   // 0..31: row group (4 rows)
    const int cg = t & 7;    // 0..7 : col group (8 cols)

    float acc[4][8];
    #pragma unroll
    for (int i = 0; i < 4; ++i)
        #pragma unroll
        for (int j = 0; j < 8; ++j) acc[i][j] = 0.f;

    for (int k0 = 0; k0 < FEAT_K; k0 += BK) {
        // Stage F tile transposed: 128 rows x 32 k = 1024 float4, 4 per thread.
        #pragma unroll
        for (int i = 0; i < 4; ++i) {
            int l = t + i * 256;          // 0..1023
            int r = l >> 3;               // 0..127
            int c4 = l & 7;               // which float4 of the 32-float k-slice
            int grow = row0 + r;
            float4 v = make_float4(0.f, 0.f, 0.f, 0.f);
            if (grow < M) v = ((const float4*)(F + (size_t)grow * FEAT_K + k0))[c4];
            sFt[c4 * 4 + 0][r] = v.x;
            sFt[c4 * 4 + 1][r] = v.y;
            sFt[c4 * 4 + 2][r] = v.z;
            sFt[c4 * 4 + 3][r] = v.w;
        }
        // Stage W tile transposed: 64 n-rows x 32 k = 512 float4, 2 per thread.
        #pragma unroll
        for (int i = 0; i < 2; ++i) {
            int l = t + i * 256;
            int n = l >> 3, c4 = l & 7;
            float4 v = ((const float4*)(W + (size_t)n * FEAT_K + k0))[c4];
            sW[c4 * 4 + 0][n] = v.x;
            sW[c4 * 4 + 1][n] = v.y;
            sW[c4 * 4 + 2][n] = v.z;
            sW[c4 * 4 + 3][n] = v.w;
        }
        __syncthreads();
        #pragma unroll
        for (int k = 0; k < BK; ++k) {
            float4 av = *(const float4*)&sFt[k][rg * 4];
            float4 b0 = *(const float4*)&sW[k][cg * 8];
            float4 b1 = *(const float4*)&sW[k][cg * 8 + 4];
            float a[4] = {av.x, av.y, av.z, av.w};
            float b[8] = {b0.x, b0.y, b0.z, b0.w, b1.x, b1.y, b1.z, b1.w};
            #pragma unroll
            for (int ii = 0; ii < 4; ++ii)
                #pragma unroll
                for (int jj = 0; jj < 8; ++jj)
                    acc[ii][jj] = fmaf(a[ii], b[jj], acc[ii][jj]);
        }
        __syncthreads();
    }

    const float scale = 1.0f / 25.0f;
    #pragma unroll
    for (int ii = 0; ii < 4; ++ii) {
        int grow = row0 + rg * 4 + ii;
        if (grow < M) {
            float4* o4 = (float4*)(o + (size_t)grow * EMB_D + cg * 8);
            float4 t0 = o4[0], t1 = o4[1];
            t0.x = t0.x * scale + acc[ii][0];
            t0.y = t0.y * scale + acc[ii][1];
            t0.z = t0.z * scale + acc[ii][2];
            t0.w = t0.w * scale + acc[ii][3];
            t1.x = t1.x * scale + acc[ii][4];
            t1.y = t1.y * scale + acc[ii][5];
            t1.z = t1.z * scale + acc[ii][6];
            t1.w = t1.w * scale + acc[ii][7];
            o4[0] = t0;
            o4[1] = t1;
        }
    }
}

// ---------------------------------------------------------------------------
extern "C" void kernel_launch(void* const* d_in, const int* in_sizes, int n_in,
                              void* d_out, int out_size, void* d_ws, size_t ws_size,
                              hipStream_t stream) {
    const int E = in_sizes[0] / 2;
    const int N = N_NODES, U = U_NODES;

    const int*   edge  = (const int*)d_in[0];
    const float* emb_u = (const float*)d_in[1];
    const float* emb_i = (const float*)d_in[2];
    const float* fu    = (const float*)d_in[3];
    const float* fi    = (const float*)d_in[4];
    const float* wu    = (const float*)d_in[5];
    const float* wi    = (const float*)d_in[6];
    const int* row = edge;
    const int* col = edge + E;

    // Workspace carve (aligned 256B). Total ~87 MB.
    char* p = (char*)d_ws;
    auto carve = [&](size_t bytes) -> void* {
        void* q = (void*)p;
        p += (bytes + 255) & ~(size_t)255;
        return q;
    };
    float* dinv    = (float*)carve((size_t)N * 4);
    int*   deg     = (int*)  carve((size_t)N * 4);
    int*   rs      = (int*)  carve((size_t)(N + 1) * 4);
    int*   cursor  = (int*)  carve((size_t)N * 4);
    int*   bsum    = (int*)  carve(1024 * 4);
    int*   csr_src = (int*)  carve((size_t)E * 4);
    float* csr_nrm = (float*)carve((size_t)E * 4);
    float* x_a     = (float*)carve((size_t)N * EMB_D * 4);
    float* x_b     = (float*)carve((size_t)N * EMB_D * 4);

    float* acc = (float*)d_out;   // acc lives in d_out: [N][64] == [u_final; i_final]

    const int NB = (N + 255) / 256;              // 586 scan blocks
    const int EB = (E + 255) / 256;              // edge blocks
    const int XB = ((N * 16) + 255) / 256;       // N*16 float4 elements

    // 1) degree
    hipMemsetAsync(deg, 0, (size_t)N * 4, stream);
    k_count<<<EB, 256, 0, stream>>>(col, deg, E);
    // 2) dinv
    k_dinv<<<NB, 256, 0, stream>>>(deg, dinv, N);
    // 3) exclusive scan deg -> rs (row starts), cursor copy
    k_scan_a<<<NB, 256, 0, stream>>>(deg, rs, bsum, N);
    k_scan_b<<<1, 1024, 0, stream>>>(bsum, NB);
    k_scan_c<<<NB, 256, 0, stream>>>(rs, bsum, cursor, N, E);
    // 4) CSR fill with precomputed norms
    k_fill<<<EB, 256, 0, stream>>>(row, col, dinv, cursor, csr_src, csr_nrm, E);
    // 5) x0 and acc init
    k_init<<<XB, 256, 0, stream>>>((const float4*)emb_u, (const float4*)emb_i,
                                   (float4*)x_a, (float4*)acc, U * 16, N * 16);
    // 6) 4 propagation layers (pull-mode, no atomics)
    float* xc = x_a; float* xn = x_b;
    for (int l = 0; l < N_LAYERS; ++l) {
        k_agg<<<XB, 256, 0, stream>>>((const float4*)xc, (float4*)xn, (float4*)acc,
                                      rs, csr_src, csr_nrm, N);
        float* t = xc; xc = xn; xn = t;
    }
    // 7) fused projection epilogue: out = out/25 + F @ W^T  (user + item in one launch)
    const int nbU = (U + BM - 1) / BM;                 // 782
    const int nbI = (N - U + BM - 1) / BM;             // 391
    k_proj<<<nbU + nbI, 256, 0, stream>>>(fu, fi, wu, wi, acc, nbU, U, N - U);
}

// Round 4
// 365.620 us; speedup vs baseline: 2.1693x; 1.2374x over previous
//
#include <hip/hip_runtime.h>

// Problem constants (match reference)
#define U_NODES 100000
#define I_NODES 50000
#define N_NODES 150000   // U + I
#define EMB_D   64
#define FEAT_K  256
#define N_LAYERS 4

typedef __attribute__((ext_vector_type(8))) short short8;
typedef __attribute__((ext_vector_type(4))) float f32x4;

// f32 -> bf16 with round-to-nearest-even (bit trick, no denorm/NaN care needed here)
static __device__ __forceinline__ unsigned short f2bf(float f) {
    unsigned u = __builtin_bit_cast(unsigned, f);
    u += 0x7fffu + ((u >> 16) & 1u);
    return (unsigned short)(u >> 16);
}
static __device__ __forceinline__ float bflo(unsigned u) {   // low bf16 of packed pair
    return __builtin_bit_cast(float, u << 16);
}
static __device__ __forceinline__ float bfhi(unsigned u) {   // high bf16 of packed pair
    return __builtin_bit_cast(float, u & 0xffff0000u);
}

// ---------------------------------------------------------------------------
// CSR build: degree count
__global__ __launch_bounds__(256) void k_count(const int* __restrict__ col,
                                               int* __restrict__ deg, int E) {
    int e = blockIdx.x * 256 + threadIdx.x;
    if (e < E) atomicAdd(&deg[col[e]], 1);
}

// dinv[i] = deg>0 ? rsqrt(deg) : 0
__global__ __launch_bounds__(256) void k_dinv(const int* __restrict__ deg,
                                              float* __restrict__ dinv, int n) {
    int i = blockIdx.x * 256 + threadIdx.x;
    if (i < n) {
        int d = deg[i];
        dinv[i] = (d > 0) ? rsqrtf((float)d) : 0.0f;
    }
}

// Scan stage A: per-block (256-elem) exclusive scan of deg -> rs, block totals -> bsum
__global__ __launch_bounds__(256) void k_scan_a(const int* __restrict__ deg,
                                                int* __restrict__ rs,
                                                int* __restrict__ bsum, int n) {
    __shared__ int wsum[4];
    int t = threadIdx.x;
    int i = blockIdx.x * 256 + t;
    int v = (i < n) ? deg[i] : 0;
    int x = v;
    #pragma unroll
    for (int off = 1; off < 64; off <<= 1) {
        int y = __shfl_up(x, off, 64);
        if ((t & 63) >= off) x += y;
    }
    if ((t & 63) == 63) wsum[t >> 6] = x;
    __syncthreads();
    int base = 0;
    #pragma unroll
    for (int w = 0; w < 4; ++w) base += (w < (t >> 6)) ? wsum[w] : 0;
    if (i < n) rs[i] = base + x - v;           // exclusive within block
    if (t == 255) bsum[blockIdx.x] = base + x; // block total
}

// Scan stage B: single block (1024 threads) exclusive scan of block sums in place
__global__ __launch_bounds__(1024) void k_scan_b(int* __restrict__ bs, int nb) {
    __shared__ int wsum[16];
    int t = threadIdx.x;
    int v = (t < nb) ? bs[t] : 0;
    int x = v;
    #pragma unroll
    for (int off = 1; off < 64; off <<= 1) {
        int y = __shfl_up(x, off, 64);
        if ((t & 63) >= off) x += y;
    }
    if ((t & 63) == 63) wsum[t >> 6] = x;
    __syncthreads();
    int base = 0;
    #pragma unroll
    for (int w = 0; w < 16; ++w) base += (w < (t >> 6)) ? wsum[w] : 0;
    if (t < nb) bs[t] = base + x - v;
}

// Scan stage C: add block offsets, copy to cursor, set rs[n]=E
__global__ __launch_bounds__(256) void k_scan_c(int* __restrict__ rs,
                                                const int* __restrict__ bsum,
                                                int* __restrict__ cursor,
                                                int n, int E) {
    int i = blockIdx.x * 256 + threadIdx.x;
    if (i < n) {
        int v = rs[i] + bsum[blockIdx.x];
        rs[i] = v;
        cursor[i] = v;
    }
    if (i == 0) rs[n] = E;
}

// CSR fill: place each edge into its destination's segment; precompute norm
__global__ __launch_bounds__(256) void k_fill(const int* __restrict__ row,
                                              const int* __restrict__ col,
                                              const float* __restrict__ dinv,
                                              int* __restrict__ cursor,
                                              int* __restrict__ csr_src,
                                              float* __restrict__ csr_nrm, int E) {
    int e = blockIdx.x * 256 + threadIdx.x;
    if (e < E) {
        int r = row[e], c = col[e];
        int p = atomicAdd(&cursor[c], 1);
        csr_src[p] = r;
        csr_nrm[p] = dinv[r] * dinv[c];
    }
}

// Convert W matrices to bf16 (once per call; 32K elements total)
__global__ __launch_bounds__(256) void k_cvtw(const float* __restrict__ wu,
                                              const float* __restrict__ wi,
                                              unsigned short* __restrict__ wub,
                                              unsigned short* __restrict__ wib) {
    int i = blockIdx.x * 256 + threadIdx.x;   // 0..32767
    if (i < EMB_D * FEAT_K) wub[i] = f2bf(wu[i]);
    else                    wib[i - EMB_D * FEAT_K] = f2bf(wi[i - EMB_D * FEAT_K]);
}

// Init: x0 (bf16) = concat(emb_users, emb_items); acc (f32, = d_out) = x0
// One thread per 8 elements.
__global__ __launch_bounds__(256) void k_init(const float4* __restrict__ eu,
                                              const float4* __restrict__ ei,
                                              uint4* __restrict__ x,
                                              float4* __restrict__ acc,
                                              int n8u, int n8) {
    int i = blockIdx.x * 256 + threadIdx.x;
    if (i >= n8) return;
    const float4* s = (i < n8u) ? (eu + (size_t)i * 2) : (ei + (size_t)(i - n8u) * 2);
    float4 p0 = s[0], p1 = s[1];
    uint4 r;
    r.x = (unsigned)f2bf(p0.x) | ((unsigned)f2bf(p0.y) << 16);
    r.y = (unsigned)f2bf(p0.z) | ((unsigned)f2bf(p0.w) << 16);
    r.z = (unsigned)f2bf(p1.x) | ((unsigned)f2bf(p1.y) << 16);
    r.w = (unsigned)f2bf(p1.z) | ((unsigned)f2bf(p1.w) << 16);
    x[i] = r;
    acc[(size_t)i * 2]     = p0;
    acc[(size_t)i * 2 + 1] = p1;
}

// Pull-mode aggregation, bf16 state: 8 lanes per node, each owns 8 bf16 (16 B).
// x_next[c] = sum_{e in CSR[c]} x_cur[src[e]] * nrm[e];  acc[c] += x_next[c]
__global__ __launch_bounds__(256) void k_agg(const uint4* __restrict__ xin,
                                             uint4* __restrict__ xout,
                                             float4* __restrict__ acc,
                                             const int* __restrict__ rs,
                                             const int* __restrict__ src,
                                             const float* __restrict__ nrm,
                                             int n_nodes) {
    int idx = blockIdx.x * 256 + threadIdx.x;
    int node = idx >> 3;
    int lane = idx & 7;
    if (node >= n_nodes) return;
    int e0 = rs[node], e1 = rs[node + 1];
    float s0 = 0.f, s1 = 0.f, s2 = 0.f, s3 = 0.f;
    float s4 = 0.f, s5 = 0.f, s6 = 0.f, s7 = 0.f;
    for (int e = e0; e < e1; ++e) {
        int sn = src[e];                      // broadcast across the 8 lanes
        float w = nrm[e];
        uint4 v = xin[(size_t)sn * 8 + lane]; // 128B coalesced per edge
        s0 = fmaf(bflo(v.x), w, s0);
        s1 = fmaf(bfhi(v.x), w, s1);
        s2 = fmaf(bflo(v.y), w, s2);
        s3 = fmaf(bfhi(v.y), w, s3);
        s4 = fmaf(bflo(v.z), w, s4);
        s5 = fmaf(bfhi(v.z), w, s5);
        s6 = fmaf(bflo(v.w), w, s6);
        s7 = fmaf(bfhi(v.w), w, s7);
    }
    uint4 r;
    r.x = (unsigned)f2bf(s0) | ((unsigned)f2bf(s1) << 16);
    r.y = (unsigned)f2bf(s2) | ((unsigned)f2bf(s3) << 16);
    r.z = (unsigned)f2bf(s4) | ((unsigned)f2bf(s5) << 16);
    r.w = (unsigned)f2bf(s6) | ((unsigned)f2bf(s7) << 16);
    xout[(size_t)node * 8 + lane] = r;
    size_t o = (size_t)node * 16 + lane * 2;
    float4 a0 = acc[o], a1 = acc[o + 1];
    a0.x += s0; a0.y += s1; a0.z += s2; a0.w += s3;
    a1.x += s4; a1.y += s5; a1.z += s6; a1.w += s7;
    acc[o] = a0;
    acc[o + 1] = a1;
}

// ---------------------------------------------------------------------------
// Projection via MFMA bf16: C[M,64] = F[M,256] @ W[64,256]^T, fused epilogue
//   out[r][c] = out[r][c]/25 + C[r][c]
// Block = 256 threads = 4 waves; wave w computes rows [row0+16w, +16), all 64
// cols, as 4 n-tiles of mfma_f32_16x16x32_bf16 over 8 k-steps.
// A-frags come straight from global F (each row used by exactly one wave);
// B-frags from the tiny bf16 W (L1-hot). No LDS, no barriers.
// Fragment layouts (16x16x32 family):
//   A: row = l&15, k = (l>>4)*8 + j      (8 consecutive bf16 per lane)
//   B: col = l&15, k = (l>>4)*8 + j
//   D: col = l&15, row = (l>>4)*4 + reg   [m89/m91-verified]
__global__ __launch_bounds__(256) void k_projm(const float* __restrict__ FU,
                                               const float* __restrict__ FI,
                                               const unsigned short* __restrict__ WUb,
                                               const unsigned short* __restrict__ WIb,
                                               float* __restrict__ out,
                                               int nbU, int U, int I) {
    const bool isU = ((int)blockIdx.x < nbU);
    const float* __restrict__ F = isU ? FU : FI;
    const uint4* __restrict__ Wb4 = (const uint4*)(isU ? WUb : WIb);
    float* __restrict__ o = isU ? out : out + (size_t)U * EMB_D;
    const int M = isU ? U : I;

    const int wave = threadIdx.x >> 6;
    const int lane = threadIdx.x & 63;
    const int l15  = lane & 15;
    const int kq   = lane >> 4;               // 0..3
    const int row0 = (isU ? (int)blockIdx.x : (int)blockIdx.x - nbU) * 64 + wave * 16;
    const int arow = row0 + l15;

    f32x4 acc0 = {0.f, 0.f, 0.f, 0.f};
    f32x4 acc1 = {0.f, 0.f, 0.f, 0.f};
    f32x4 acc2 = {0.f, 0.f, 0.f, 0.f};
    f32x4 acc3 = {0.f, 0.f, 0.f, 0.f};

    #pragma unroll
    for (int ks = 0; ks < 8; ++ks) {
        const int k = ks * 32 + kq * 8;
        // A fragment: 8 consecutive f32 from F[arow][k..k+7] -> bf16
        short8 av = (short8)0;
        if (arow < M) {
            const float4* fp = (const float4*)(F + (size_t)arow * FEAT_K + k);
            float4 a0 = fp[0], a1 = fp[1];
            av[0] = (short)f2bf(a0.x); av[1] = (short)f2bf(a0.y);
            av[2] = (short)f2bf(a0.z); av[3] = (short)f2bf(a0.w);
            av[4] = (short)f2bf(a1.x); av[5] = (short)f2bf(a1.y);
            av[6] = (short)f2bf(a1.z); av[7] = (short)f2bf(a1.w);
        }
        // B fragments: W[col][k..k+7] as bf16x8 (16B), col = nt*16 + l15
        #pragma unroll
        for (int nt = 0; nt < 4; ++nt) {
            int bcol = nt * 16 + l15;
            uint4 b = Wb4[(size_t)bcol * (FEAT_K / 8) + ks * 4 + kq];
            short8 bv = __builtin_bit_cast(short8, b);
            if (nt == 0) acc0 = __builtin_amdgcn_mfma_f32_16x16x32_bf16(av, bv, acc0, 0, 0, 0);
            if (nt == 1) acc1 = __builtin_amdgcn_mfma_f32_16x16x32_bf16(av, bv, acc1, 0, 0, 0);
            if (nt == 2) acc2 = __builtin_amdgcn_mfma_f32_16x16x32_bf16(av, bv, acc2, 0, 0, 0);
            if (nt == 3) acc3 = __builtin_amdgcn_mfma_f32_16x16x32_bf16(av, bv, acc3, 0, 0, 0);
        }
    }

    // Epilogue: D[row=(kq*4+r)][col=nt*16+l15]; out = out/25 + D
    const float scale = 1.0f / 25.0f;
    #pragma unroll
    for (int r = 0; r < 4; ++r) {
        int grow = row0 + kq * 4 + r;
        if (grow < M) {
            float* op = o + (size_t)grow * EMB_D + l15;
            op[0]  = op[0]  * scale + acc0[r];
            op[16] = op[16] * scale + acc1[r];
            op[32] = op[32] * scale + acc2[r];
            op[48] = op[48] * scale + acc3[r];
        }
    }
}

// ---------------------------------------------------------------------------
extern "C" void kernel_launch(void* const* d_in, const int* in_sizes, int n_in,
                              void* d_out, int out_size, void* d_ws, size_t ws_size,
                              hipStream_t stream) {
    const int E = in_sizes[0] / 2;
    const int N = N_NODES, U = U_NODES;

    const int*   edge  = (const int*)d_in[0];
    const float* emb_u = (const float*)d_in[1];
    const float* emb_i = (const float*)d_in[2];
    const float* fu    = (const float*)d_in[3];
    const float* fi    = (const float*)d_in[4];
    const float* wu    = (const float*)d_in[5];
    const float* wi    = (const float*)d_in[6];
    const int* row = edge;
    const int* col = edge + E;

    // Workspace carve (aligned 256B).
    char* p = (char*)d_ws;
    auto carve = [&](size_t bytes) -> void* {
        void* q = (void*)p;
        p += (bytes + 255) & ~(size_t)255;
        return q;
    };
    float* dinv    = (float*)carve((size_t)N * 4);
    int*   deg     = (int*)  carve((size_t)N * 4);
    int*   rs      = (int*)  carve((size_t)(N + 1) * 4);
    int*   cursor  = (int*)  carve((size_t)N * 4);
    int*   bsum    = (int*)  carve(1024 * 4);
    int*   csr_src = (int*)  carve((size_t)E * 4);
    float* csr_nrm = (float*)carve((size_t)E * 4);
    unsigned short* wub = (unsigned short*)carve((size_t)EMB_D * FEAT_K * 2);
    unsigned short* wib = (unsigned short*)carve((size_t)EMB_D * FEAT_K * 2);
    uint4* x_a = (uint4*)carve((size_t)N * EMB_D * 2);   // bf16 layer state
    uint4* x_b = (uint4*)carve((size_t)N * EMB_D * 2);

    float* acc = (float*)d_out;   // acc lives in d_out: [N][64] == [u_final; i_final]

    const int NB  = (N + 255) / 256;             // scan blocks
    const int EB  = (E + 255) / 256;             // edge blocks
    const int XB8 = ((N * 8) + 255) / 256;       // N*8 16B-lanes

    // 1) degree
    hipMemsetAsync(deg, 0, (size_t)N * 4, stream);
    k_count<<<EB, 256, 0, stream>>>(col, deg, E);
    // 2) dinv
    k_dinv<<<NB, 256, 0, stream>>>(deg, dinv, N);
    // 3) exclusive scan deg -> rs (row starts), cursor copy
    k_scan_a<<<NB, 256, 0, stream>>>(deg, rs, bsum, N);
    k_scan_b<<<1, 1024, 0, stream>>>(bsum, NB);
    k_scan_c<<<NB, 256, 0, stream>>>(rs, bsum, cursor, N, E);
    // 4) CSR fill with precomputed norms
    k_fill<<<EB, 256, 0, stream>>>(row, col, dinv, cursor, csr_src, csr_nrm, E);
    // 4b) W -> bf16
    k_cvtw<<<(2 * EMB_D * FEAT_K) / 256, 256, 0, stream>>>(wu, wi, wub, wib);
    // 5) x0 (bf16) and acc (f32) init
    k_init<<<XB8, 256, 0, stream>>>((const float4*)emb_u, (const float4*)emb_i,
                                    x_a, (float4*)acc, U * 8, N * 8);
    // 6) 4 propagation layers (pull-mode, no atomics, bf16 state)
    uint4* xc = x_a; uint4* xn = x_b;
    for (int l = 0; l < N_LAYERS; ++l) {
        k_agg<<<XB8, 256, 0, stream>>>(xc, xn, (float4*)acc, rs, csr_src, csr_nrm, N);
        uint4* t = xc; xc = xn; xn = t;
    }
    // 7) fused MFMA projection epilogue: out = out/25 + F @ W^T (user+item, one launch)
    const int nbU = (U + 63) / 64;               // 1563
    const int nbI = (N - U + 63) / 64;           // 782
    k_projm<<<nbU + nbI, 256, 0, stream>>>(fu, fi, wub, wib, acc, nbU, U, N - U);
}

// Round 6
// 291.630 us; speedup vs baseline: 2.7197x; 1.2537x over previous
//
#include <hip/hip_runtime.h>

// Problem constants (match reference)
#define U_NODES 100000
#define I_NODES 50000
#define N_NODES 150000   // U + I
#define EMB_D   64
#define FEAT_K  256
#define N_LAYERS 4

typedef __attribute__((ext_vector_type(8))) short short8;
typedef __attribute__((ext_vector_type(4))) float f32x4;

// f32 -> bf16 round-to-nearest-even (bit trick)
static __device__ __forceinline__ unsigned short f2bf(float f) {
    unsigned u = __builtin_bit_cast(unsigned, f);
    u += 0x7fffu + ((u >> 16) & 1u);
    return (unsigned short)(u >> 16);
}
static __device__ __forceinline__ float bflo(unsigned u) {
    return __builtin_bit_cast(float, u << 16);
}
static __device__ __forceinline__ float bfhi(unsigned u) {
    return __builtin_bit_cast(float, u & 0xffff0000u);
}

// ---------------------------------------------------------------------------
// CSR build: degree count
__global__ __launch_bounds__(256) void k_count(const int* __restrict__ col,
                                               int* __restrict__ deg, int E) {
    int e = blockIdx.x * 256 + threadIdx.x;
    if (e < E) atomicAdd(&deg[col[e]], 1);
}

__global__ __launch_bounds__(256) void k_dinv(const int* __restrict__ deg,
                                              float* __restrict__ dinv, int n) {
    int i = blockIdx.x * 256 + threadIdx.x;
    if (i < n) {
        int d = deg[i];
        dinv[i] = (d > 0) ? rsqrtf((float)d) : 0.0f;
    }
}

__global__ __launch_bounds__(256) void k_scan_a(const int* __restrict__ deg,
                                                int* __restrict__ rs,
                                                int* __restrict__ bsum, int n) {
    __shared__ int wsum[4];
    int t = threadIdx.x;
    int i = blockIdx.x * 256 + t;
    int v = (i < n) ? deg[i] : 0;
    int x = v;
    #pragma unroll
    for (int off = 1; off < 64; off <<= 1) {
        int y = __shfl_up(x, off, 64);
        if ((t & 63) >= off) x += y;
    }
    if ((t & 63) == 63) wsum[t >> 6] = x;
    __syncthreads();
    int base = 0;
    #pragma unroll
    for (int w = 0; w < 4; ++w) base += (w < (t >> 6)) ? wsum[w] : 0;
    if (i < n) rs[i] = base + x - v;
    if (t == 255) bsum[blockIdx.x] = base + x;
}

__global__ __launch_bounds__(1024) void k_scan_b(int* __restrict__ bs, int nb) {
    __shared__ int wsum[16];
    int t = threadIdx.x;
    int v = (t < nb) ? bs[t] : 0;
    int x = v;
    #pragma unroll
    for (int off = 1; off < 64; off <<= 1) {
        int y = __shfl_up(x, off, 64);
        if ((t & 63) >= off) x += y;
    }
    if ((t & 63) == 63) wsum[t >> 6] = x;
    __syncthreads();
    int base = 0;
    #pragma unroll
    for (int w = 0; w < 16; ++w) base += (w < (t >> 6)) ? wsum[w] : 0;
    if (t < nb) bs[t] = base + x - v;
}

__global__ __launch_bounds__(256) void k_scan_c(int* __restrict__ rs,
                                                const int* __restrict__ bsum,
                                                int* __restrict__ cursor,
                                                int n, int E) {
    int i = blockIdx.x * 256 + threadIdx.x;
    if (i < n) {
        int v = rs[i] + bsum[blockIdx.x];
        rs[i] = v;
        cursor[i] = v;
    }
    if (i == 0) rs[n] = E;
}

__global__ __launch_bounds__(256) void k_fill(const int* __restrict__ row,
                                              const int* __restrict__ col,
                                              const float* __restrict__ dinv,
                                              int* __restrict__ cursor,
                                              int* __restrict__ csr_src,
                                              float* __restrict__ csr_nrm, int E) {
    int e = blockIdx.x * 256 + threadIdx.x;
    if (e < E) {
        int r = row[e], c = col[e];
        int p = atomicAdd(&cursor[c], 1);
        csr_src[p] = r;
        csr_nrm[p] = dinv[r] * dinv[c];
    }
}

// Convert W matrices to bf16 (once per call; 32K elements total)
__global__ __launch_bounds__(256) void k_cvtw(const float* __restrict__ wu,
                                              const float* __restrict__ wi,
                                              unsigned short* __restrict__ wub,
                                              unsigned short* __restrict__ wib) {
    int i = blockIdx.x * 256 + threadIdx.x;
    if (i < EMB_D * FEAT_K) wub[i] = f2bf(wu[i]);
    else                    wib[i - EMB_D * FEAT_K] = f2bf(wi[i - EMB_D * FEAT_K]);
}

// Init: x0 (bf16) = concat(emb_users, emb_items). One thread per 8 elements.
__global__ __launch_bounds__(256) void k_init(const float4* __restrict__ eu,
                                              const float4* __restrict__ ei,
                                              uint4* __restrict__ x,
                                              int n8u, int n8) {
    int i = blockIdx.x * 256 + threadIdx.x;
    if (i >= n8) return;
    const float4* s = (i < n8u) ? (eu + (size_t)i * 2) : (ei + (size_t)(i - n8u) * 2);
    float4 p0 = s[0], p1 = s[1];
    uint4 r;
    r.x = (unsigned)f2bf(p0.x) | ((unsigned)f2bf(p0.y) << 16);
    r.y = (unsigned)f2bf(p0.z) | ((unsigned)f2bf(p0.w) << 16);
    r.z = (unsigned)f2bf(p1.x) | ((unsigned)f2bf(p1.y) << 16);
    r.w = (unsigned)f2bf(p1.z) | ((unsigned)f2bf(p1.w) << 16);
    x[i] = r;
}

// NOTE: macro params use trailing-underscore names so they can never collide
// with the .x/.y/.z/.w member tokens (R5 compile bug).
#define ACC8(v_, w_)                       \
    s0 = fmaf(bflo((v_).x), (w_), s0);     \
    s1 = fmaf(bfhi((v_).x), (w_), s1);     \
    s2 = fmaf(bflo((v_).y), (w_), s2);     \
    s3 = fmaf(bfhi((v_).y), (w_), s3);     \
    s4 = fmaf(bflo((v_).z), (w_), s4);     \
    s5 = fmaf(bfhi((v_).z), (w_), s5);     \
    s6 = fmaf(bflo((v_).w), (w_), s6);     \
    s7 = fmaf(bfhi((v_).w), (w_), s7);

// Pull-mode aggregation (layers 1..3), bf16 state: 8 lanes/node, 16B/lane.
// Unroll-4 edge loop -> 4 outstanding gathers.
__global__ __launch_bounds__(256) void k_agg(const uint4* __restrict__ xin,
                                             uint4* __restrict__ xout,
                                             const int* __restrict__ rs,
                                             const int* __restrict__ src,
                                             const float* __restrict__ nrm,
                                             int n_nodes) {
    int idx = blockIdx.x * 256 + threadIdx.x;
    int node = idx >> 3;
    int lane = idx & 7;
    if (node >= n_nodes) return;
    int e0 = rs[node], e1 = rs[node + 1];
    float s0 = 0.f, s1 = 0.f, s2 = 0.f, s3 = 0.f;
    float s4 = 0.f, s5 = 0.f, s6 = 0.f, s7 = 0.f;
    int e = e0;
    for (; e + 4 <= e1; e += 4) {
        int   na = src[e],   nb = src[e+1],  nc = src[e+2],  nd = src[e+3];
        float wa = nrm[e],   wb = nrm[e+1],  wc = nrm[e+2],  wd = nrm[e+3];
        uint4 va = xin[(size_t)na * 8 + lane];
        uint4 vb = xin[(size_t)nb * 8 + lane];
        uint4 vc = xin[(size_t)nc * 8 + lane];
        uint4 vd = xin[(size_t)nd * 8 + lane];
        ACC8(va, wa) ACC8(vb, wb) ACC8(vc, wc) ACC8(vd, wd)
    }
    for (; e < e1; ++e) {
        int sn = src[e];
        float w = nrm[e];
        uint4 v = xin[(size_t)sn * 8 + lane];
        ACC8(v, w)
    }
    uint4 r;
    r.x = (unsigned)f2bf(s0) | ((unsigned)f2bf(s1) << 16);
    r.y = (unsigned)f2bf(s2) | ((unsigned)f2bf(s3) << 16);
    r.z = (unsigned)f2bf(s4) | ((unsigned)f2bf(s5) << 16);
    r.w = (unsigned)f2bf(s6) | ((unsigned)f2bf(s7) << 16);
    xout[(size_t)node * 8 + lane] = r;
}

// Layer 4 + fused sum: s = gather(x3); out_row = (emb + x1 + x2 + x3 + s)/25
// Written directly to d_out (f32). All row reads/writes coalesced.
__global__ __launch_bounds__(256) void k_agg4(const uint4* __restrict__ x3,
                                              const uint4* __restrict__ x1,
                                              const uint4* __restrict__ x2,
                                              const float* __restrict__ embU,
                                              const float* __restrict__ embI,
                                              float* __restrict__ outp,
                                              const int* __restrict__ rs,
                                              const int* __restrict__ src,
                                              const float* __restrict__ nrm,
                                              int n_nodes, int U) {
    int idx = blockIdx.x * 256 + threadIdx.x;
    int node = idx >> 3;
    int lane = idx & 7;
    if (node >= n_nodes) return;
    int e0 = rs[node], e1 = rs[node + 1];
    float s0 = 0.f, s1 = 0.f, s2 = 0.f, s3 = 0.f;
    float s4 = 0.f, s5 = 0.f, s6 = 0.f, s7 = 0.f;
    int e = e0;
    for (; e + 4 <= e1; e += 4) {
        int   na = src[e],   nb = src[e+1],  nc = src[e+2],  nd = src[e+3];
        float wa = nrm[e],   wb = nrm[e+1],  wc = nrm[e+2],  wd = nrm[e+3];
        uint4 va = x3[(size_t)na * 8 + lane];
        uint4 vb = x3[(size_t)nb * 8 + lane];
        uint4 vc = x3[(size_t)nc * 8 + lane];
        uint4 vd = x3[(size_t)nd * 8 + lane];
        ACC8(va, wa) ACC8(vb, wb) ACC8(vc, wc) ACC8(vd, wd)
    }
    for (; e < e1; ++e) {
        int sn = src[e];
        float w = nrm[e];
        uint4 v = x3[(size_t)sn * 8 + lane];
        ACC8(v, w)
    }
    // row reads: x1,x2,x3 bf16 + emb f32
    uint4 v1 = x1[(size_t)node * 8 + lane];
    uint4 v2 = x2[(size_t)node * 8 + lane];
    uint4 v3 = x3[(size_t)node * 8 + lane];
    const float* eb = (node < U) ? (embU + (size_t)node * EMB_D)
                                 : (embI + (size_t)(node - U) * EMB_D);
    float4 ea = ((const float4*)eb)[lane * 2];
    float4 eb2 = ((const float4*)eb)[lane * 2 + 1];
    const float sc = 1.0f / 25.0f;
    float4 o0, o1;
    o0.x = (ea.x  + bflo(v1.x) + bflo(v2.x) + bflo(v3.x) + s0) * sc;
    o0.y = (ea.y  + bfhi(v1.x) + bfhi(v2.x) + bfhi(v3.x) + s1) * sc;
    o0.z = (ea.z  + bflo(v1.y) + bflo(v2.y) + bflo(v3.y) + s2) * sc;
    o0.w = (ea.w  + bfhi(v1.y) + bfhi(v2.y) + bfhi(v3.y) + s3) * sc;
    o1.x = (eb2.x + bflo(v1.z) + bflo(v2.z) + bflo(v3.z) + s4) * sc;
    o1.y = (eb2.y + bfhi(v1.z) + bfhi(v2.z) + bfhi(v3.z) + s5) * sc;
    o1.z = (eb2.z + bflo(v1.w) + bflo(v2.w) + bflo(v3.w) + s6) * sc;
    o1.w = (eb2.w + bfhi(v1.w) + bfhi(v2.w) + bfhi(v3.w) + s7) * sc;
    float4* op = (float4*)(outp + (size_t)node * EMB_D) + lane * 2;
    op[0] = o0;
    op[1] = o1;
}

// ---------------------------------------------------------------------------
// Projection via MFMA bf16: out[r][c] += (F @ W^T)[r][c]   (sum/25 already in out)
// Block = 4 waves; wave owns 16 rows x 64 cols. All 16 A float4 loads issued
// up-front into registers (max memory ILP); W staged once into LDS in
// [kk][nt][c] layout -> lane-contiguous ds_read_b128, conflict-free.
// Fragment layouts (16x16x32 bf16, m89/m91-verified):
//   A: row = l&15, k = (l>>4)*8 + j ;  B: col = l&15, k = (l>>4)*8 + j
//   D: col = l&15, row = (l>>4)*4 + reg
__global__ __launch_bounds__(256) void k_projm(const float* __restrict__ FU,
                                               const float* __restrict__ FI,
                                               const unsigned short* __restrict__ WUb,
                                               const unsigned short* __restrict__ WIb,
                                               float* __restrict__ out,
                                               int nbU, int U, int I) {
    __shared__ uint4 sB[2048];   // 32 KB: [kk(32)][nt(4)][c(16)]
    const bool isU = ((int)blockIdx.x < nbU);
    const uint4* __restrict__ Wb4 = (const uint4*)(isU ? WUb : WIb);
    #pragma unroll
    for (int i = 0; i < 8; ++i) {
        int d = threadIdx.x + i * 256;          // 0..2047
        int kk = d >> 6, nt = (d >> 4) & 3, c = d & 15;
        sB[d] = Wb4[(size_t)(nt * 16 + c) * 32 + kk];
    }

    const float* __restrict__ F = isU ? FU : FI;
    float* __restrict__ o = isU ? out : out + (size_t)U * EMB_D;
    const int M = isU ? U : I;
    const int wave = threadIdx.x >> 6;
    const int lane = threadIdx.x & 63;
    const int l15  = lane & 15;
    const int kq   = lane >> 4;
    const int row0 = (isU ? (int)blockIdx.x : (int)blockIdx.x - nbU) * 64 + wave * 16;
    const int arow = min(row0 + l15, M - 1);     // clamp: dup rows, discarded at store
    const float* fb = F + (size_t)arow * FEAT_K + kq * 8;

    // issue ALL 16 A loads (64 VGPR) before the barrier
    float4 a0 = ((const float4*)(fb +   0))[0], a1 = ((const float4*)(fb +   0))[1];
    float4 a2 = ((const float4*)(fb +  32))[0], a3 = ((const float4*)(fb +  32))[1];
    float4 a4 = ((const float4*)(fb +  64))[0], a5 = ((const float4*)(fb +  64))[1];
    float4 a6 = ((const float4*)(fb +  96))[0], a7 = ((const float4*)(fb +  96))[1];
    float4 a8 = ((const float4*)(fb + 128))[0], a9 = ((const float4*)(fb + 128))[1];
    float4 aa = ((const float4*)(fb + 160))[0], ab = ((const float4*)(fb + 160))[1];
    float4 ac = ((const float4*)(fb + 192))[0], ad = ((const float4*)(fb + 192))[1];
    float4 ae = ((const float4*)(fb + 224))[0], af = ((const float4*)(fb + 224))[1];

    __syncthreads();

    f32x4 acc0 = {0.f, 0.f, 0.f, 0.f};
    f32x4 acc1 = {0.f, 0.f, 0.f, 0.f};
    f32x4 acc2 = {0.f, 0.f, 0.f, 0.f};
    f32x4 acc3 = {0.f, 0.f, 0.f, 0.f};

#define CVT2(d_, lo_, hi_) asm("v_cvt_pk_bf16_f32 %0, %1, %2" : "=v"(d_) : "v"(lo_), "v"(hi_))
#define KSTEP(ks_, xa_, ya_)                                                   \
    {                                                                          \
        unsigned p0, p1, p2, p3;                                               \
        CVT2(p0, (xa_).x, (xa_).y); CVT2(p1, (xa_).z, (xa_).w);                \
        CVT2(p2, (ya_).x, (ya_).y); CVT2(p3, (ya_).z, (ya_).w);                \
        uint4 up; up.x = p0; up.y = p1; up.z = p2; up.w = p3;                  \
        short8 av = __builtin_bit_cast(short8, up);                            \
        const uint4* sbk = &sB[((ks_) * 4 + kq) * 64];                         \
        short8 b0 = __builtin_bit_cast(short8, sbk[l15]);                      \
        short8 b1 = __builtin_bit_cast(short8, sbk[16 + l15]);                 \
        short8 b2 = __builtin_bit_cast(short8, sbk[32 + l15]);                 \
        short8 b3 = __builtin_bit_cast(short8, sbk[48 + l15]);                 \
        acc0 = __builtin_amdgcn_mfma_f32_16x16x32_bf16(av, b0, acc0, 0, 0, 0); \
        acc1 = __builtin_amdgcn_mfma_f32_16x16x32_bf16(av, b1, acc1, 0, 0, 0); \
        acc2 = __builtin_amdgcn_mfma_f32_16x16x32_bf16(av, b2, acc2, 0, 0, 0); \
        acc3 = __builtin_amdgcn_mfma_f32_16x16x32_bf16(av, b3, acc3, 0, 0, 0); \
    }

    KSTEP(0, a0, a1) KSTEP(1, a2, a3) KSTEP(2, a4, a5) KSTEP(3, a6, a7)
    KSTEP(4, a8, a9) KSTEP(5, aa, ab) KSTEP(6, ac, ad) KSTEP(7, ae, af)
#undef KSTEP
#undef CVT2

    // Epilogue: out = out + D  (out already holds sum/25 from k_agg4)
    #pragma unroll
    for (int r = 0; r < 4; ++r) {
        int grow = row0 + kq * 4 + r;
        if (grow < M) {
            float* op = o + (size_t)grow * EMB_D + l15;
            op[0]  += acc0[r];
            op[16] += acc1[r];
            op[32] += acc2[r];
            op[48] += acc3[r];
        }
    }
}

// ---------------------------------------------------------------------------
extern "C" void kernel_launch(void* const* d_in, const int* in_sizes, int n_in,
                              void* d_out, int out_size, void* d_ws, size_t ws_size,
                              hipStream_t stream) {
    const int E = in_sizes[0] / 2;
    const int N = N_NODES, U = U_NODES;

    const int*   edge  = (const int*)d_in[0];
    const float* emb_u = (const float*)d_in[1];
    const float* emb_i = (const float*)d_in[2];
    const float* fu    = (const float*)d_in[3];
    const float* fi    = (const float*)d_in[4];
    const float* wu    = (const float*)d_in[5];
    const float* wi    = (const float*)d_in[6];
    const int* row = edge;
    const int* col = edge + E;

    // Workspace carve (aligned 256B). ~88 MB total.
    char* p = (char*)d_ws;
    auto carve = [&](size_t bytes) -> void* {
        void* q = (void*)p;
        p += (bytes + 255) & ~(size_t)255;
        return q;
    };
    float* dinv    = (float*)carve((size_t)N * 4);
    int*   deg     = (int*)  carve((size_t)N * 4);
    int*   rs      = (int*)  carve((size_t)(N + 1) * 4);
    int*   cursor  = (int*)  carve((size_t)N * 4);
    int*   bsum    = (int*)  carve(1024 * 4);
    int*   csr_src = (int*)  carve((size_t)E * 4);
    float* csr_nrm = (float*)carve((size_t)E * 4);
    unsigned short* wub = (unsigned short*)carve((size_t)EMB_D * FEAT_K * 2);
    unsigned short* wib = (unsigned short*)carve((size_t)EMB_D * FEAT_K * 2);
    uint4* x0 = (uint4*)carve((size_t)N * EMB_D * 2);   // bf16 layer states
    uint4* x1 = (uint4*)carve((size_t)N * EMB_D * 2);
    uint4* x2 = (uint4*)carve((size_t)N * EMB_D * 2);
    uint4* x3 = (uint4*)carve((size_t)N * EMB_D * 2);

    float* outp = (float*)d_out;   // [N][64] == [u_final; i_final]

    const int NB  = (N + 255) / 256;
    const int EB  = (E + 255) / 256;
    const int XB8 = ((N * 8) + 255) / 256;

    hipMemsetAsync(deg, 0, (size_t)N * 4, stream);
    k_count<<<EB, 256, 0, stream>>>(col, deg, E);
    k_dinv<<<NB, 256, 0, stream>>>(deg, dinv, N);
    k_scan_a<<<NB, 256, 0, stream>>>(deg, rs, bsum, N);
    k_scan_b<<<1, 1024, 0, stream>>>(bsum, NB);
    k_scan_c<<<NB, 256, 0, stream>>>(rs, bsum, cursor, N, E);
    k_fill<<<EB, 256, 0, stream>>>(row, col, dinv, cursor, csr_src, csr_nrm, E);
    k_cvtw<<<(2 * EMB_D * FEAT_K) / 256, 256, 0, stream>>>(wu, wi, wub, wib);
    k_init<<<XB8, 256, 0, stream>>>((const float4*)emb_u, (const float4*)emb_i,
                                    x0, U * 8, N * 8);
    // layers 1..3: pure propagation, bf16 state
    k_agg<<<XB8, 256, 0, stream>>>(x0, x1, rs, csr_src, csr_nrm, N);
    k_agg<<<XB8, 256, 0, stream>>>(x1, x2, rs, csr_src, csr_nrm, N);
    k_agg<<<XB8, 256, 0, stream>>>(x2, x3, rs, csr_src, csr_nrm, N);
    // layer 4 fused with the (x0..x4) sum and 1/25 scale -> d_out
    k_agg4<<<XB8, 256, 0, stream>>>(x3, x1, x2, emb_u, emb_i, outp,
                                    rs, csr_src, csr_nrm, N, U);
    // projection: out += F @ W^T (user + item in one launch)
    const int nbU = (U + 63) / 64;               // 1563
    const int nbI = (N - U + 63) / 64;           // 782
    k_projm<<<nbU + nbI, 256, 0, stream>>>(fu, fi, wub, wib, outp, nbU, U, N - U);
}

// Round 7
// 275.521 us; speedup vs baseline: 2.8787x; 1.0585x over previous
//
#include <hip/hip_runtime.h>

// Problem constants (match reference)
#define U_NODES 100000
#define I_NODES 50000
#define N_NODES 150000   // U + I
#define EMB_D   64
#define FEAT_K  256
#define N_LAYERS 4

typedef __attribute__((ext_vector_type(8))) short short8;
typedef __attribute__((ext_vector_type(4))) float f32x4;

// f32 -> bf16 round-to-nearest-even (bit trick)
static __device__ __forceinline__ unsigned short f2bf(float f) {
    unsigned u = __builtin_bit_cast(unsigned, f);
    u += 0x7fffu + ((u >> 16) & 1u);
    return (unsigned short)(u >> 16);
}
static __device__ __forceinline__ float bflo(unsigned u) {
    return __builtin_bit_cast(float, u << 16);
}
static __device__ __forceinline__ float bfhi(unsigned u) {
    return __builtin_bit_cast(float, u & 0xffff0000u);
}

// ---------------------------------------------------------------------------
__global__ __launch_bounds__(256) void k_count(const int* __restrict__ col,
                                               int* __restrict__ deg, int E) {
    int e = blockIdx.x * 256 + threadIdx.x;
    if (e < E) atomicAdd(&deg[col[e]], 1);
}

__global__ __launch_bounds__(256) void k_dinv(const int* __restrict__ deg,
                                              float* __restrict__ dinv, int n) {
    int i = blockIdx.x * 256 + threadIdx.x;
    if (i < n) {
        int d = deg[i];
        dinv[i] = (d > 0) ? rsqrtf((float)d) : 0.0f;
    }
}

__global__ __launch_bounds__(256) void k_scan_a(const int* __restrict__ deg,
                                                int* __restrict__ rs,
                                                int* __restrict__ bsum, int n) {
    __shared__ int wsum[4];
    int t = threadIdx.x;
    int i = blockIdx.x * 256 + t;
    int v = (i < n) ? deg[i] : 0;
    int x = v;
    #pragma unroll
    for (int off = 1; off < 64; off <<= 1) {
        int y = __shfl_up(x, off, 64);
        if ((t & 63) >= off) x += y;
    }
    if ((t & 63) == 63) wsum[t >> 6] = x;
    __syncthreads();
    int base = 0;
    #pragma unroll
    for (int w = 0; w < 4; ++w) base += (w < (t >> 6)) ? wsum[w] : 0;
    if (i < n) rs[i] = base + x - v;
    if (t == 255) bsum[blockIdx.x] = base + x;
}

__global__ __launch_bounds__(1024) void k_scan_b(int* __restrict__ bs, int nb) {
    __shared__ int wsum[16];
    int t = threadIdx.x;
    int v = (t < nb) ? bs[t] : 0;
    int x = v;
    #pragma unroll
    for (int off = 1; off < 64; off <<= 1) {
        int y = __shfl_up(x, off, 64);
        if ((t & 63) >= off) x += y;
    }
    if ((t & 63) == 63) wsum[t >> 6] = x;
    __syncthreads();
    int base = 0;
    #pragma unroll
    for (int w = 0; w < 16; ++w) base += (w < (t >> 6)) ? wsum[w] : 0;
    if (t < nb) bs[t] = base + x - v;
}

__global__ __launch_bounds__(256) void k_scan_c(int* __restrict__ rs,
                                                const int* __restrict__ bsum,
                                                int* __restrict__ cursor,
                                                int n, int E) {
    int i = blockIdx.x * 256 + threadIdx.x;
    if (i < n) {
        int v = rs[i] + bsum[blockIdx.x];
        rs[i] = v;
        cursor[i] = v;
    }
    if (i == 0) rs[n] = E;
}

// CSR fill: ONE scattered 8B write per edge (src, norm packed as int2).
__global__ __launch_bounds__(256) void k_fill(const int* __restrict__ row,
                                              const int* __restrict__ col,
                                              const float* __restrict__ dinv,
                                              int* __restrict__ cursor,
                                              int2* __restrict__ csr, int E) {
    int e = blockIdx.x * 256 + threadIdx.x;
    if (e < E) {
        int r = row[e], c = col[e];
        int p = atomicAdd(&cursor[c], 1);
        int2 v;
        v.x = r;
        v.y = __builtin_bit_cast(int, dinv[r] * dinv[c]);
        csr[p] = v;
    }
}

// Convert W matrices to bf16 (once per call; 32K elements total)
__global__ __launch_bounds__(256) void k_cvtw(const float* __restrict__ wu,
                                              const float* __restrict__ wi,
                                              unsigned short* __restrict__ wub,
                                              unsigned short* __restrict__ wib) {
    int i = blockIdx.x * 256 + threadIdx.x;
    if (i < EMB_D * FEAT_K) wub[i] = f2bf(wu[i]);
    else                    wib[i - EMB_D * FEAT_K] = f2bf(wi[i - EMB_D * FEAT_K]);
}

// Init: x0 (bf16) = concat(emb_users, emb_items). One thread per 8 elements.
__global__ __launch_bounds__(256) void k_init(const float4* __restrict__ eu,
                                              const float4* __restrict__ ei,
                                              uint4* __restrict__ x,
                                              int n8u, int n8) {
    int i = blockIdx.x * 256 + threadIdx.x;
    if (i >= n8) return;
    const float4* s = (i < n8u) ? (eu + (size_t)i * 2) : (ei + (size_t)(i - n8u) * 2);
    float4 p0 = s[0], p1 = s[1];
    uint4 r;
    r.x = (unsigned)f2bf(p0.x) | ((unsigned)f2bf(p0.y) << 16);
    r.y = (unsigned)f2bf(p0.z) | ((unsigned)f2bf(p0.w) << 16);
    r.z = (unsigned)f2bf(p1.x) | ((unsigned)f2bf(p1.y) << 16);
    r.w = (unsigned)f2bf(p1.z) | ((unsigned)f2bf(p1.w) << 16);
    x[i] = r;
}

// NOTE: macro params use trailing-underscore names (R5 lesson: never collide
// with .x/.y/.z/.w member tokens).
#define ACC8(v_, w_)                       \
    s0 = fmaf(bflo((v_).x), (w_), s0);     \
    s1 = fmaf(bfhi((v_).x), (w_), s1);     \
    s2 = fmaf(bflo((v_).y), (w_), s2);     \
    s3 = fmaf(bfhi((v_).y), (w_), s3);     \
    s4 = fmaf(bflo((v_).z), (w_), s4);     \
    s5 = fmaf(bfhi((v_).z), (w_), s5);     \
    s6 = fmaf(bflo((v_).w), (w_), s6);     \
    s7 = fmaf(bfhi((v_).w), (w_), s7);

// Masked 4-wide gather round: always 4 outstanding gathers; OOB lanes are
// clamped to the last edge with weight zeroed (wasted loads hit same line).
#define GATHER4(xsrc_, ep_, em_)                                              \
    {                                                                         \
        int i0_ = (ep_), i1_ = min((ep_) + 1, (em_));                         \
        int i2_ = min((ep_) + 2, (em_)), i3_ = min((ep_) + 3, (em_));         \
        int2 pa_ = csr[i0_], pb_ = csr[i1_], pc_ = csr[i2_], pd_ = csr[i3_];  \
        float wa_ = __builtin_bit_cast(float, pa_.y);                         \
        float wb_ = ((ep_) + 1 <= (em_)) ? __builtin_bit_cast(float, pb_.y) : 0.f; \
        float wc_ = ((ep_) + 2 <= (em_)) ? __builtin_bit_cast(float, pc_.y) : 0.f; \
        float wd_ = ((ep_) + 3 <= (em_)) ? __builtin_bit_cast(float, pd_.y) : 0.f; \
        uint4 va_ = (xsrc_)[(size_t)pa_.x * 8 + lane];                        \
        uint4 vb_ = (xsrc_)[(size_t)pb_.x * 8 + lane];                        \
        uint4 vc_ = (xsrc_)[(size_t)pc_.x * 8 + lane];                        \
        uint4 vd_ = (xsrc_)[(size_t)pd_.x * 8 + lane];                        \
        ACC8(va_, wa_) ACC8(vb_, wb_) ACC8(vc_, wc_) ACC8(vd_, wd_)           \
    }

// Pull-mode aggregation (layers 1..3), bf16 state: 8 lanes/node, 16B/lane.
__global__ __launch_bounds__(256) void k_agg(const uint4* __restrict__ xin,
                                             uint4* __restrict__ xout,
                                             const int* __restrict__ rs,
                                             const int2* __restrict__ csr,
                                             int n_nodes) {
    int idx = blockIdx.x * 256 + threadIdx.x;
    int node = idx >> 3;
    int lane = idx & 7;
    if (node >= n_nodes) return;
    int e0 = rs[node], e1 = rs[node + 1];
    float s0 = 0.f, s1 = 0.f, s2 = 0.f, s3 = 0.f;
    float s4 = 0.f, s5 = 0.f, s6 = 0.f, s7 = 0.f;
    int em = e1 - 1;
    for (int ep = e0; ep < e1; ep += 4) GATHER4(xin, ep, em)
    uint4 r;
    r.x = (unsigned)f2bf(s0) | ((unsigned)f2bf(s1) << 16);
    r.y = (unsigned)f2bf(s2) | ((unsigned)f2bf(s3) << 16);
    r.z = (unsigned)f2bf(s4) | ((unsigned)f2bf(s5) << 16);
    r.w = (unsigned)f2bf(s6) | ((unsigned)f2bf(s7) << 16);
    xout[(size_t)node * 8 + lane] = r;
}

// Layer 4 + fused sum: s = gather(x3); out_row = (emb + x1 + x2 + x3 + s)/25
__global__ __launch_bounds__(256) void k_agg4(const uint4* __restrict__ x3,
                                              const uint4* __restrict__ x1,
                                              const uint4* __restrict__ x2,
                                              const float* __restrict__ embU,
                                              const float* __restrict__ embI,
                                              float* __restrict__ outp,
                                              const int* __restrict__ rs,
                                              const int2* __restrict__ csr,
                                              int n_nodes, int U) {
    int idx = blockIdx.x * 256 + threadIdx.x;
    int node = idx >> 3;
    int lane = idx & 7;
    if (node >= n_nodes) return;
    int e0 = rs[node], e1 = rs[node + 1];
    float s0 = 0.f, s1 = 0.f, s2 = 0.f, s3 = 0.f;
    float s4 = 0.f, s5 = 0.f, s6 = 0.f, s7 = 0.f;
    int em = e1 - 1;
    for (int ep = e0; ep < e1; ep += 4) GATHER4(x3, ep, em)
    // row reads: x1,x2,x3 bf16 + emb f32
    uint4 v1 = x1[(size_t)node * 8 + lane];
    uint4 v2 = x2[(size_t)node * 8 + lane];
    uint4 v3 = x3[(size_t)node * 8 + lane];
    const float* ebp = (node < U) ? (embU + (size_t)node * EMB_D)
                                  : (embI + (size_t)(node - U) * EMB_D);
    float4 ea = ((const float4*)ebp)[lane * 2];
    float4 eb2 = ((const float4*)ebp)[lane * 2 + 1];
    const float sc = 1.0f / 25.0f;
    float4 o0, o1;
    o0.x = (ea.x  + bflo(v1.x) + bflo(v2.x) + bflo(v3.x) + s0) * sc;
    o0.y = (ea.y  + bfhi(v1.x) + bfhi(v2.x) + bfhi(v3.x) + s1) * sc;
    o0.z = (ea.z  + bflo(v1.y) + bflo(v2.y) + bflo(v3.y) + s2) * sc;
    o0.w = (ea.w  + bfhi(v1.y) + bfhi(v2.y) + bfhi(v3.y) + s3) * sc;
    o1.x = (eb2.x + bflo(v1.z) + bflo(v2.z) + bflo(v3.z) + s4) * sc;
    o1.y = (eb2.y + bfhi(v1.z) + bfhi(v2.z) + bfhi(v3.z) + s5) * sc;
    o1.z = (eb2.z + bflo(v1.w) + bflo(v2.w) + bflo(v3.w) + s6) * sc;
    o1.w = (eb2.w + bfhi(v1.w) + bfhi(v2.w) + bfhi(v3.w) + s7) * sc;
    float4* op = (float4*)(outp + (size_t)node * EMB_D) + lane * 2;
    op[0] = o0;
    op[1] = o1;
}

// ---------------------------------------------------------------------------
// Projection via MFMA bf16: out[r][c] += (F @ W^T)[r][c]   (sum/25 already in out)
// 4 waves/block; wave owns 16 rows x 64 cols; 16 A float4 loads up-front;
// W staged once in LDS [kk][nt][c] -> lane-contiguous ds_read_b128.
// Fragment layouts (16x16x32 bf16, m89/m91-verified):
//   A: row = l&15, k = (l>>4)*8 + j ;  B: col = l&15, k = (l>>4)*8 + j
//   D: col = l&15, row = (l>>4)*4 + reg
__global__ __launch_bounds__(256) void k_projm(const float* __restrict__ FU,
                                               const float* __restrict__ FI,
                                               const unsigned short* __restrict__ WUb,
                                               const unsigned short* __restrict__ WIb,
                                               float* __restrict__ out,
                                               int nbU, int U, int I) {
    __shared__ uint4 sB[2048];   // 32 KB: [kk(32)][nt(4)][c(16)]
    const bool isU = ((int)blockIdx.x < nbU);
    const uint4* __restrict__ Wb4 = (const uint4*)(isU ? WUb : WIb);
    #pragma unroll
    for (int i = 0; i < 8; ++i) {
        int d = threadIdx.x + i * 256;          // 0..2047
        int kk = d >> 6, nt = (d >> 4) & 3, c = d & 15;
        sB[d] = Wb4[(size_t)(nt * 16 + c) * 32 + kk];
    }

    const float* __restrict__ F = isU ? FU : FI;
    float* __restrict__ o = isU ? out : out + (size_t)U * EMB_D;
    const int M = isU ? U : I;
    const int wave = threadIdx.x >> 6;
    const int lane = threadIdx.x & 63;
    const int l15  = lane & 15;
    const int kq   = lane >> 4;
    const int row0 = (isU ? (int)blockIdx.x : (int)blockIdx.x - nbU) * 64 + wave * 16;
    const int arow = min(row0 + l15, M - 1);     // clamp: dup rows, discarded at store
    const float* fb = F + (size_t)arow * FEAT_K + kq * 8;

    // issue ALL 16 A loads (64 VGPR) before the barrier
    float4 a0 = ((const float4*)(fb +   0))[0], a1 = ((const float4*)(fb +   0))[1];
    float4 a2 = ((const float4*)(fb +  32))[0], a3 = ((const float4*)(fb +  32))[1];
    float4 a4 = ((const float4*)(fb +  64))[0], a5 = ((const float4*)(fb +  64))[1];
    float4 a6 = ((const float4*)(fb +  96))[0], a7 = ((const float4*)(fb +  96))[1];
    float4 a8 = ((const float4*)(fb + 128))[0], a9 = ((const float4*)(fb + 128))[1];
    float4 aa = ((const float4*)(fb + 160))[0], ab = ((const float4*)(fb + 160))[1];
    float4 ac = ((const float4*)(fb + 192))[0], ad = ((const float4*)(fb + 192))[1];
    float4 ae = ((const float4*)(fb + 224))[0], af = ((const float4*)(fb + 224))[1];

    __syncthreads();

    f32x4 acc0 = {0.f, 0.f, 0.f, 0.f};
    f32x4 acc1 = {0.f, 0.f, 0.f, 0.f};
    f32x4 acc2 = {0.f, 0.f, 0.f, 0.f};
    f32x4 acc3 = {0.f, 0.f, 0.f, 0.f};

#define CVT2(d_, lo_, hi_) asm("v_cvt_pk_bf16_f32 %0, %1, %2" : "=v"(d_) : "v"(lo_), "v"(hi_))
#define KSTEP(ks_, xa_, ya_)                                                   \
    {                                                                          \
        unsigned p0, p1, p2, p3;                                               \
        CVT2(p0, (xa_).x, (xa_).y); CVT2(p1, (xa_).z, (xa_).w);                \
        CVT2(p2, (ya_).x, (ya_).y); CVT2(p3, (ya_).z, (ya_).w);                \
        uint4 up; up.x = p0; up.y = p1; up.z = p2; up.w = p3;                  \
        short8 av = __builtin_bit_cast(short8, up);                            \
        const uint4* sbk = &sB[((ks_) * 4 + kq) * 64];                         \
        short8 b0 = __builtin_bit_cast(short8, sbk[l15]);                      \
        short8 b1 = __builtin_bit_cast(short8, sbk[16 + l15]);                 \
        short8 b2 = __builtin_bit_cast(short8, sbk[32 + l15]);                 \
        short8 b3 = __builtin_bit_cast(short8, sbk[48 + l15]);                 \
        acc0 = __builtin_amdgcn_mfma_f32_16x16x32_bf16(av, b0, acc0, 0, 0, 0); \
        acc1 = __builtin_amdgcn_mfma_f32_16x16x32_bf16(av, b1, acc1, 0, 0, 0); \
        acc2 = __builtin_amdgcn_mfma_f32_16x16x32_bf16(av, b2, acc2, 0, 0, 0); \
        acc3 = __builtin_amdgcn_mfma_f32_16x16x32_bf16(av, b3, acc3, 0, 0, 0); \
    }

    KSTEP(0, a0, a1) KSTEP(1, a2, a3) KSTEP(2, a4, a5) KSTEP(3, a6, a7)
    KSTEP(4, a8, a9) KSTEP(5, aa, ab) KSTEP(6, ac, ad) KSTEP(7, ae, af)
#undef KSTEP
#undef CVT2

    #pragma unroll
    for (int r = 0; r < 4; ++r) {
        int grow = row0 + kq * 4 + r;
        if (grow < M) {
            float* op = o + (size_t)grow * EMB_D + l15;
            op[0]  += acc0[r];
            op[16] += acc1[r];
            op[32] += acc2[r];
            op[48] += acc3[r];
        }
    }
}

// ---------------------------------------------------------------------------
extern "C" void kernel_launch(void* const* d_in, const int* in_sizes, int n_in,
                              void* d_out, int out_size, void* d_ws, size_t ws_size,
                              hipStream_t stream) {
    const int E = in_sizes[0] / 2;
    const int N = N_NODES, U = U_NODES;

    const int*   edge  = (const int*)d_in[0];
    const float* emb_u = (const float*)d_in[1];
    const float* emb_i = (const float*)d_in[2];
    const float* fu    = (const float*)d_in[3];
    const float* fi    = (const float*)d_in[4];
    const float* wu    = (const float*)d_in[5];
    const float* wi    = (const float*)d_in[6];
    const int* row = edge;
    const int* col = edge + E;

    // Workspace carve (aligned 256B). ~88 MB total.
    char* p = (char*)d_ws;
    auto carve = [&](size_t bytes) -> void* {
        void* q = (void*)p;
        p += (bytes + 255) & ~(size_t)255;
        return q;
    };
    float* dinv    = (float*)carve((size_t)N * 4);
    int*   deg     = (int*)  carve((size_t)N * 4);
    int*   rs      = (int*)  carve((size_t)(N + 1) * 4);
    int*   cursor  = (int*)  carve((size_t)N * 4);
    int*   bsum    = (int*)  carve(1024 * 4);
    int2*  csr     = (int2*) carve((size_t)E * 8);      // packed (src, norm)
    unsigned short* wub = (unsigned short*)carve((size_t)EMB_D * FEAT_K * 2);
    unsigned short* wib = (unsigned short*)carve((size_t)EMB_D * FEAT_K * 2);
    uint4* x0 = (uint4*)carve((size_t)N * EMB_D * 2);   // bf16 layer states
    uint4* x1 = (uint4*)carve((size_t)N * EMB_D * 2);
    uint4* x2 = (uint4*)carve((size_t)N * EMB_D * 2);
    uint4* x3 = (uint4*)carve((size_t)N * EMB_D * 2);

    float* outp = (float*)d_out;   // [N][64] == [u_final; i_final]

    const int NB  = (N + 255) / 256;
    const int EB  = (E + 255) / 256;
    const int XB8 = ((N * 8) + 255) / 256;

    hipMemsetAsync(deg, 0, (size_t)N * 4, stream);
    k_count<<<EB, 256, 0, stream>>>(col, deg, E);
    k_dinv<<<NB, 256, 0, stream>>>(deg, dinv, N);
    k_scan_a<<<NB, 256, 0, stream>>>(deg, rs, bsum, N);
    k_scan_b<<<1, 1024, 0, stream>>>(bsum, NB);
    k_scan_c<<<NB, 256, 0, stream>>>(rs, bsum, cursor, N, E);
    k_fill<<<EB, 256, 0, stream>>>(row, col, dinv, cursor, csr, E);
    k_cvtw<<<(2 * EMB_D * FEAT_K) / 256, 256, 0, stream>>>(wu, wi, wub, wib);
    k_init<<<XB8, 256, 0, stream>>>((const float4*)emb_u, (const float4*)emb_i,
                                    x0, U * 8, N * 8);
    // layers 1..3: pure propagation, bf16 state
    k_agg<<<XB8, 256, 0, stream>>>(x0, x1, rs, csr, N);
    k_agg<<<XB8, 256, 0, stream>>>(x1, x2, rs, csr, N);
    k_agg<<<XB8, 256, 0, stream>>>(x2, x3, rs, csr, N);
    // layer 4 fused with the (x0..x4) sum and 1/25 scale -> d_out
    k_agg4<<<XB8, 256, 0, stream>>>(x3, x1, x2, emb_u, emb_i, outp, rs, csr, N, U);
    // projection: out += F @ W^T (user + item in one launch)
    const int nbU = (U + 63) / 64;               // 1563
    const int nbI = (N - U + 63) / 64;           // 782
    k_projm<<<nbU + nbI, 256, 0, stream>>>(fu, fi, wub, wib, outp, nbU, U, N - U);
}